// Round 2
// baseline (314.394 us; speedup 1.0000x reference)
//
#include <hip/hip_runtime.h>

#define N_ROWS 4194304
#define RPT 8            // rows per thread; loop (not unrolled) keeps I-cache hot
#define BLOCK 256

__device__ __forceinline__ float rrelu(float v) {
    // slope 0.0025 < 1  =>  leaky relu == max(v, slope*v)   (2 VALU ops)
    return fmaxf(v, 0.0025f * v);
}

struct Weights {
    const float *W_in,  *b_in,  *W_h1,  *b_h1,  *W_h2, *b_h2, *W_h3, *b_h3,
                *W_h4,  *b_h4,  *W_h5,  *b_h5,  *W_enc, *b_enc,
                *W_h6,  *b_h6,  *W_h7,  *b_h7,  *W_h8, *b_h8, *W_h9, *b_h9,
                *W_h10, *b_h10, *W_dec, *b_dec;
};

// x = x + lin(rrelu(lin(x, Wa, ba)), Wb, bb)   (all 4x4), single row
__device__ __forceinline__ void resblock(float x[4],
                                         const float* __restrict__ Wa,
                                         const float* __restrict__ ba,
                                         const float* __restrict__ Wb,
                                         const float* __restrict__ bb) {
    float t[4];
#pragma unroll
    for (int j = 0; j < 4; ++j) {
        float acc = ba[j];
#pragma unroll
        for (int i = 0; i < 4; ++i) acc = fmaf(x[i], Wa[i * 4 + j], acc);
        t[j] = rrelu(acc);
    }
#pragma unroll
    for (int j = 0; j < 4; ++j) {
        float acc = bb[j];
#pragma unroll
        for (int i = 0; i < 4; ++i) acc = fmaf(t[i], Wb[i * 4 + j], acc);
        x[j] += acc;
    }
}

// full network for ONE row; all indices constant after inlining -> registers
__device__ __forceinline__ void net_row(const float xin[8], const Weights& w,
                                        float& e_out, float d[8]) {
    // in: 8->8, rrelu
    float t8[8];
#pragma unroll
    for (int j = 0; j < 8; ++j) {
        float acc = w.b_in[j];
#pragma unroll
        for (int i = 0; i < 8; ++i) acc = fmaf(xin[i], w.W_in[i * 8 + j], acc);
        t8[j] = rrelu(acc);
    }
    // h1: 8->4, no activation
    float x[4];
#pragma unroll
    for (int j = 0; j < 4; ++j) {
        float acc = w.b_h1[j];
#pragma unroll
        for (int i = 0; i < 8; ++i) acc = fmaf(t8[i], w.W_h1[i * 4 + j], acc);
        x[j] = acc;
    }
    resblock(x, w.W_h2, w.b_h2, w.W_h3, w.b_h3);
    resblock(x, w.W_h4, w.b_h4, w.W_h5, w.b_h5);
    // encode: 4->1, rrelu
    float e = w.b_enc[0];
#pragma unroll
    for (int i = 0; i < 4; ++i) e = fmaf(x[i], w.W_enc[i], e);
    e = rrelu(e);
    e_out = e;
    // h6: 1->4, rrelu
#pragma unroll
    for (int j = 0; j < 4; ++j) x[j] = rrelu(fmaf(e, w.W_h6[j], w.b_h6[j]));
    resblock(x, w.W_h7, w.b_h7, w.W_h8, w.b_h8);
    resblock(x, w.W_h9, w.b_h9, w.W_h10, w.b_h10);
    // decode: 4->8, rrelu
#pragma unroll
    for (int j = 0; j < 8; ++j) {
        float acc = w.b_dec[j];
#pragma unroll
        for (int i = 0; i < 4; ++i) acc = fmaf(x[i], w.W_dec[i * 8 + j], acc);
        d[j] = rrelu(acc);
    }
}

__global__ __launch_bounds__(BLOCK) void ann_fused_kernel(
    const float* __restrict__ x_in, float* __restrict__ out, Weights w) {
    const int tid = blockIdx.x * BLOCK + threadIdx.x;
    const int T = N_ROWS / RPT;  // rows handled: tid + k*T (coalesced per instr)

    // one-iteration-ahead register double buffer for the input row
    const float4* p0 = reinterpret_cast<const float4*>(x_in) + (size_t)tid * 2;
    float4 a_next = p0[0];
    float4 b_next = p0[1];

#pragma unroll 1
    for (int k = 0; k < RPT; ++k) {
        float4 a = a_next, b = b_next;
        if (k + 1 < RPT) {  // uniform branch, no divergence
            const float4* pn = reinterpret_cast<const float4*>(x_in) +
                               ((size_t)tid + (size_t)(k + 1) * T) * 2;
            a_next = pn[0];
            b_next = pn[1];
        }
        float xin[8] = {a.x, a.y, a.z, a.w, b.x, b.y, b.z, b.w};
        float e, d[8];
        net_row(xin, w, e, d);

        const int row = tid + k * T;
        out[row] = e;  // encode stream: 1 dword/lane, coalesced
        float4* q = reinterpret_cast<float4*>(out + N_ROWS + (size_t)row * 8);
        q[0] = make_float4(d[0], d[1], d[2], d[3]);
        q[1] = make_float4(d[4], d[5], d[6], d[7]);
    }
}

extern "C" void kernel_launch(void* const* d_in, const int* in_sizes, int n_in,
                              void* d_out, int out_size, void* d_ws, size_t ws_size,
                              hipStream_t stream) {
    const float* x_in = (const float*)d_in[0];
    Weights w;
    w.W_in  = (const float*)d_in[1];  w.b_in  = (const float*)d_in[2];
    w.W_h1  = (const float*)d_in[3];  w.b_h1  = (const float*)d_in[4];
    w.W_h2  = (const float*)d_in[5];  w.b_h2  = (const float*)d_in[6];
    w.W_h3  = (const float*)d_in[7];  w.b_h3  = (const float*)d_in[8];
    w.W_h4  = (const float*)d_in[9];  w.b_h4  = (const float*)d_in[10];
    w.W_h5  = (const float*)d_in[11]; w.b_h5  = (const float*)d_in[12];
    w.W_enc = (const float*)d_in[13]; w.b_enc = (const float*)d_in[14];
    w.W_h6  = (const float*)d_in[15]; w.b_h6  = (const float*)d_in[16];
    w.W_h7  = (const float*)d_in[17]; w.b_h7  = (const float*)d_in[18];
    w.W_h8  = (const float*)d_in[19]; w.b_h8  = (const float*)d_in[20];
    w.W_h9  = (const float*)d_in[21]; w.b_h9  = (const float*)d_in[22];
    w.W_h10 = (const float*)d_in[23]; w.b_h10 = (const float*)d_in[24];
    w.W_dec = (const float*)d_in[25]; w.b_dec = (const float*)d_in[26];
    float* out = (float*)d_out;

    const int total_threads = N_ROWS / RPT;
    dim3 grid(total_threads / BLOCK), block(BLOCK);
    ann_fused_kernel<<<grid, block, 0, stream>>>(x_in, out, w);
}